// Round 6
// baseline (256.351 us; speedup 1.0000x reference)
//
#include <hip/hip_runtime.h>

#define SCALE 0.125f

constexpr int L_ = 1024, T_ = 1024, D_ = 64, HB_ = 64, QB = 32;

using f32x4 = __attribute__((ext_vector_type(4))) float;
using half8 = __attribute__((ext_vector_type(8))) _Float16;
using half4 = __attribute__((ext_vector_type(4))) _Float16;

// One block = 32 q-rows x full T for one (h,b). 256 threads = 4 waves:
// wave w -> rowtile rt=w>>1 (16 rows), t-half th=w&1 (64 of each 128-t iter).
// Phase A: swapped QK^T (LDS-staged K), +prev, exp -> E into LDS (f16,
// swizzled, 64KB). Z partials in regs, exchanged via LDS.
// Phase B: E from LDS, normalize in f32, att f32x4 stores from regs,
// PV MFMA with LDS V^T, cross-th O reduction in LDS.
// E never touches HBM; prev read exactly once. LDS = 80 KB -> 2 blocks/CU.
__global__ __launch_bounds__(256, 2) void attn_fused(
    const float* __restrict__ q, const float* __restrict__ kk,
    const float* __restrict__ vv, const float* __restrict__ prev,
    float* __restrict__ out, float* __restrict__ att) {
  __shared__ __align__(16) unsigned char smem[81920];
  unsigned char* Elb = smem;          // 65536 B: E[32][1024] f16, swizzled
  unsigned char* KVb = smem + 65536;  // 16384 B: K tile / V^T tile / zb / obuf

  const int ltile = blockIdx.x;   // 0..31
  const int hb    = blockIdx.y;   // 0..63
  const int tid = threadIdx.x;
  const int w = tid >> 6, l = tid & 63, l15 = l & 15, lg = l >> 4;
  const int rt = w >> 1, th = w & 1;
  const int qloc = rt * 16 + l15;            // lane's q row within block
  const int qrow = ltile * QB + qloc;        // global q row

  // swizzled LDS addressing (XOR of row-low-bits into 16B-slot bits)
  auto elp = [&](int qq, int t) {            // E[32][1024] f16
    return Elb + qq * 2048 + (((unsigned)t * 2) ^ (((unsigned)qq & 7) << 4));
  };
  auto kp_ = [&](int row, int dbyte) {       // K tile [128 t][64 d] f16
    return KVb + row * 128 + ((unsigned)dbyte ^ (((unsigned)row & 7) << 4));
  };
  auto vp_ = [&](int d, int tbyte) {         // V^T tile [64 d][128 t] f16
    return KVb + d * 256 + ((unsigned)tbyte ^ (((unsigned)d & 7) << 4));
  };

  // ---- Q B-fragment (swapped QK^T): lane holds Q[qrow][f*32 + lg*8 + e]
  half8 qb[2];
  {
    const float* qp = q + ((size_t)hb * L_ + qrow) * D_ + lg * 8;
#pragma unroll
    for (int f = 0; f < 2; ++f)
#pragma unroll
      for (int e = 0; e < 8; ++e) qb[f][e] = (_Float16)qp[f * 32 + e];
  }

  const float* kbase = kk + (size_t)hb * T_ * D_;
  const float* vbase = vv + (size_t)hb * T_ * D_;
  const float* prow  = prev + ((size_t)hb * L_ + qrow) * (size_t)T_;

  // ---- cooperative staging: tile = 128 t-rows x 64 d (f32 -> f16)
  const int sr = tid >> 1;          // t-row 0..127
  const int sh = (tid & 1) * 32;    // d base 0 or 32
  float4 kreg[8];
  auto gload = [&](const float* base, int c) {
    const float* p = base + (size_t)(c * 128 + sr) * D_ + sh;
#pragma unroll
    for (int i = 0; i < 8; ++i) kreg[i] = *(const float4*)(p + i * 4);
  };
  auto kwrite = [&]() {
#pragma unroll
    for (int j = 0; j < 4; ++j) {   // 16B swizzled writes, d = sh+j*8..+7
      const float* f = (const float*)&kreg[j * 2];
      half8 hv;
#pragma unroll
      for (int e = 0; e < 8; ++e) hv[e] = (_Float16)f[e];
      *(half8*)kp_(sr, (sh + j * 8) * 2) = hv;
    }
  };
  auto vwrite = [&]() {             // transpose: V[t][d] -> Vt[d][t]
    const float* f = (const float*)kreg;
#pragma unroll
    for (int e = 0; e < 32; ++e)
      *(_Float16*)vp_(sh + e, sr * 2) = (_Float16)f[e];
  };

  // ---- prev prefetch, depth 2 (3 rotating static buffers)
  f32x4 pbuf[3][4];
  auto pload = [&](int c, int s) {
#pragma unroll
    for (int nt = 0; nt < 4; ++nt)
      pbuf[s][nt] =
          *(const f32x4*)(prow + c * 128 + th * 64 + nt * 16 + lg * 4);
  };

  // ======================= Phase A: scores -> E(LDS) ======================
  gload(kbase, 0);
  kwrite();
  pload(0, 0);
  pload(1, 1);

  float zsum = 0.f;

#pragma unroll
  for (int c = 0; c < 8; ++c) {
    __syncthreads();                       // K tile c staged for all
    if (c < 7) {
      gload(kbase, c + 1);                 // issue next K tile early
      if (c < 6) pload(c + 2, (c + 2) % 3);
    } else {
      gload(vbase, 0);                     // prefetch V tile 0 for phase B
    }

#pragma unroll
    for (int nt = 0; nt < 4; ++nt) {
      const int trow = th * 64 + nt * 16 + l15;   // K-tile row (t)
      half8 ka0 = *(const half8*)kp_(trow, lg * 16);
      half8 ka1 = *(const half8*)kp_(trow, 64 + lg * 16);
      f32x4 acc = {0.f, 0.f, 0.f, 0.f};
      acc = __builtin_amdgcn_mfma_f32_16x16x32_f16(ka0, qb[0], acc, 0, 0, 0);
      acc = __builtin_amdgcn_mfma_f32_16x16x32_f16(ka1, qb[1], acc, 0, 0, 0);

      // acc[i] = S^T[t = c*128+th*64+nt*16+lg*4+i][q = qrow]
      f32x4 pv = pbuf[c % 3][nt];
      float e0 = __expf(acc[0] * SCALE + pv[0]);
      float e1 = __expf(acc[1] * SCALE + pv[1]);
      float e2 = __expf(acc[2] * SCALE + pv[2]);
      float e3 = __expf(acc[3] * SCALE + pv[3]);
      zsum += (e0 + e1) + (e2 + e3);
      half4 ev;
      ev[0] = (_Float16)e0; ev[1] = (_Float16)e1;
      ev[2] = (_Float16)e2; ev[3] = (_Float16)e3;
      *(half4*)elp(qloc, c * 128 + th * 64 + nt * 16 + lg * 4) = ev;
    }

    __syncthreads();                       // all done reading K tile c
    if (c < 7) kwrite();                   // stage tile c+1
  }

  // ======================= Z exchange (via KVb) ===========================
  zsum += __shfl_xor(zsum, 16, 64);
  zsum += __shfl_xor(zsum, 32, 64);        // Z partial for (qloc, th-half)
  float* zb = (float*)KVb;
  if (lg == 0) zb[w * 16 + l15] = zsum;
  __syncthreads();
  const float rzq = 1.0f / (zb[rt * 32 + l15] + zb[rt * 32 + 16 + l15]);
  __syncthreads();                         // zb reads done before V clobbers
  vwrite();                                // stage V^T tile 0

  // ======================= Phase B: att + PV ==============================
  f32x4 oacc[4];
#pragma unroll
  for (int nd = 0; nd < 4; ++nd) oacc[nd] = (f32x4){0.f, 0.f, 0.f, 0.f};

  float* attw = att + ((size_t)hb * L_ + qrow) * (size_t)T_ + th * 64;

#pragma unroll
  for (int c = 0; c < 8; ++c) {
    __syncthreads();                       // V^T tile c staged
    if (c < 7) gload(vbase, c + 1);        // issue next V tile early

#pragma unroll
    for (int ks = 0; ks < 2; ++ks) {
      half8 ea =
          *(const half8*)elp(qloc, c * 128 + th * 64 + ks * 32 + lg * 8);
      // normalize in f32; att store direct from regs; build f16 A-frag
      f32x4 s0, s1;
      half8 af;
#pragma unroll
      for (int e = 0; e < 4; ++e) {
        float v0 = (float)ea[e] * rzq;
        float v1 = (float)ea[4 + e] * rzq;
        s0[e] = v0; s1[e] = v1;
        af[e] = (_Float16)v0;
        af[4 + e] = (_Float16)v1;
      }
      *(f32x4*)(attw + c * 128 + ks * 32 + lg * 8) = s0;
      *(f32x4*)(attw + c * 128 + ks * 32 + lg * 8 + 4) = s1;

#pragma unroll
      for (int nd = 0; nd < 4; ++nd) {
        half8 vb =
            *(const half8*)vp_(nd * 16 + l15,
                               (th * 64 + ks * 32 + lg * 8) * 2);
        oacc[nd] =
            __builtin_amdgcn_mfma_f32_16x16x32_f16(af, vb, oacc[nd], 0, 0, 0);
      }
    }

    __syncthreads();                       // all done reading V^T tile c
    if (c < 7) vwrite();                   // stage tile c+1
  }

  // ======================= O cross-th reduce + store ======================
  float* ob = (float*)KVb;                 // 32 q x 64 d f32 = 8 KB
  if (th == 1) {
#pragma unroll
    for (int nd = 0; nd < 4; ++nd)
#pragma unroll
      for (int i = 0; i < 4; ++i)
        ob[(rt * 16 + lg * 4 + i) * 64 + nd * 16 + l15] = oacc[nd][i];
  }
  __syncthreads();
  if (th == 0) {
    float* outw =
        out + ((size_t)hb * L_ + ltile * QB + rt * 16 + lg * 4) * (size_t)D_;
#pragma unroll
    for (int nd = 0; nd < 4; ++nd)
#pragma unroll
      for (int i = 0; i < 4; ++i)
        outw[(size_t)i * D_ + nd * 16 + l15] =
            oacc[nd][i] + ob[(rt * 16 + lg * 4 + i) * 64 + nd * 16 + l15];
  }
}

extern "C" void kernel_launch(void* const* d_in, const int* in_sizes, int n_in,
                              void* d_out, int out_size, void* d_ws,
                              size_t ws_size, hipStream_t stream) {
  const float* q    = (const float*)d_in[0];  // (H,B,L,D)
  const float* k    = (const float*)d_in[1];  // (H,B,T,D)
  const float* v    = (const float*)d_in[2];  // (H,B,T,D)
  const float* prev = (const float*)d_in[3];  // (H,B,L,T)

  float* out = (float*)d_out;                 // (H,B,L,D)
  float* att = out + (size_t)HB_ * L_ * D_;   // (H,B,L,T)

  dim3 grid(L_ / QB, HB_);
  attn_fused<<<grid, 256, 0, stream>>>(q, k, v, prev, out, att);
}

// Round 7
// 242.441 us; speedup vs baseline: 1.0574x; 1.0574x over previous
//
#include <hip/hip_runtime.h>

#define SCALE 0.125f

constexpr int L_ = 1024, T_ = 1024, D_ = 64, HB_ = 64, QB = 16;

using f32x4 = __attribute__((ext_vector_type(4))) float;
using half8 = __attribute__((ext_vector_type(8))) _Float16;
using half4 = __attribute__((ext_vector_type(4))) _Float16;

// One block = 16 q-rows x full T for one (h,b). 4 waves; in the score step
// wave w owns t-subtile w*16..+15 of each 64-t chunk; in the PV step wave w
// owns d-block w*16..+15. Merged loop per chunk:
//   B1(tiles ready) -> issue next K/V/prev loads -> QK^T+exp -> E->LDS
//   B2(E ready)     -> PV MFMA (unnormalized; scaled by 1/Z at the end)
//   B3(V consumed)  -> ds_write next tiles
// Phase B (barrier-free): normalize E from LDS, stream att stores.
// LDS ~50.5 KB -> 3 blocks/CU (12 waves/CU). Padded tiles (no swizzle).
__global__ __launch_bounds__(256, 3) void attn_fused(
    const float* __restrict__ q, const float* __restrict__ kk,
    const float* __restrict__ vv, const float* __restrict__ prev,
    float* __restrict__ out, float* __restrict__ att) {
  __shared__ __align__(16) _Float16 El[QB][1032];  // 33024 B, unnormalized E
  __shared__ __align__(16) _Float16 Ks[64][72];    // 9216 B, K chunk rows
  __shared__ __align__(16) _Float16 Vt[64][72];    // 9216 B, V^T chunk [d][t]
  __shared__ float zb[4][16];                      // per-wave Z partials

  const int ltile = blockIdx.x;   // 0..63
  const int hb    = blockIdx.y;   // 0..63
  const int tid = threadIdx.x;
  const int w = tid >> 6, l = tid & 63, l15 = l & 15, lg = l >> 4;
  const int qrow = ltile * QB + l15;

  // Q B-frag (swapped QK^T): lane holds Q[qrow][f*32 + lg*8 + e]
  half8 qb2[2];
  {
    const float* qp = q + ((size_t)hb * L_ + qrow) * D_ + lg * 8;
#pragma unroll
    for (int f = 0; f < 2; ++f)
#pragma unroll
      for (int e = 0; e < 8; ++e) qb2[f][e] = (_Float16)qp[f * 32 + e];
  }

  const float* prow =
      prev + ((size_t)hb * L_ + qrow) * (size_t)T_ + w * 16 + lg * 4;
  const float* kbase = kk + (size_t)hb * T_ * D_;
  const float* vbase = vv + (size_t)hb * T_ * D_;

  // cooperative staging (64 t-rows x 64 d per chunk)
  const int sr = tid >> 2;        // t-row 0..63
  const int sc = (tid & 3) * 16;  // K d-col base (contiguous 16)
  const int dj = (tid & 3) * 4;   // V d interleave base

  float4 kq[4], vq[4];
  auto kload = [&](int c) {
    const float* p = kbase + (size_t)(c * 64 + sr) * D_ + sc;
#pragma unroll
    for (int i = 0; i < 4; ++i) kq[i] = *(const float4*)(p + i * 4);
  };
  auto vload = [&](int c) {
    const float* p = vbase + (size_t)(c * 64 + sr) * D_;
#pragma unroll
    for (int i = 0; i < 4; ++i) vq[i] = *(const float4*)(p + i * 16 + dj);
  };
  auto kwrite = [&]() {  // two packed b128 writes
    half8 h0, h1;
    const float* f0 = (const float*)&kq[0];
    const float* f1 = (const float*)&kq[2];
#pragma unroll
    for (int e = 0; e < 8; ++e) { h0[e] = (_Float16)f0[e]; h1[e] = (_Float16)f1[e]; }
    *(half8*)&Ks[sr][sc] = h0;
    *(half8*)&Ks[sr][sc + 8] = h1;
  };
  auto vwrite = [&]() {  // transpose scatter (r5-proven pattern)
#pragma unroll
    for (int i = 0; i < 4; ++i) {
      Vt[i * 16 + dj + 0][sr] = (_Float16)vq[i].x;
      Vt[i * 16 + dj + 1][sr] = (_Float16)vq[i].y;
      Vt[i * 16 + dj + 2][sr] = (_Float16)vq[i].z;
      Vt[i * 16 + dj + 3][sr] = (_Float16)vq[i].w;
    }
  };

  f32x4 pb[2];
  auto pload = [&](int c) { pb[c & 1] = *(const f32x4*)(prow + c * 64); };

  // prologue: stage chunk 0, prefetch prev 0
  kload(0); vload(0); pload(0);
  kwrite(); vwrite();

  float zsum = 0.f;
  f32x4 oacc = {0.f, 0.f, 0.f, 0.f};

#pragma unroll 4
  for (int c = 0; c < 16; ++c) {
    __syncthreads();                       // K/V tile c staged for all
    f32x4 pv = pb[c & 1];
    if (c < 15) { kload(c + 1); vload(c + 1); pload(c + 1); }

    // QK^T (swapped): A = K rows t, B = Q. acc[i] = S^T[t][q=qrow]
    const int trow = w * 16 + l15;
    half8 ka0 = *(const half8*)&Ks[trow][lg * 8];
    half8 ka1 = *(const half8*)&Ks[trow][32 + lg * 8];
    f32x4 acc = {0.f, 0.f, 0.f, 0.f};
    acc = __builtin_amdgcn_mfma_f32_16x16x32_f16(ka0, qb2[0], acc, 0, 0, 0);
    acc = __builtin_amdgcn_mfma_f32_16x16x32_f16(ka1, qb2[1], acc, 0, 0, 0);

    float e0 = __expf(acc[0] * SCALE + pv[0]);
    float e1 = __expf(acc[1] * SCALE + pv[1]);
    float e2 = __expf(acc[2] * SCALE + pv[2]);
    float e3 = __expf(acc[3] * SCALE + pv[3]);
    zsum += (e0 + e1) + (e2 + e3);
    half4 ev;
    ev[0] = (_Float16)e0; ev[1] = (_Float16)e1;
    ev[2] = (_Float16)e2; ev[3] = (_Float16)e3;
    *(half4*)&El[l15][c * 64 + w * 16 + lg * 4] = ev;

    __syncthreads();                       // E(c) visible; K(c) consumed

    // PV: wave w owns d-block w. A-frag from El, B-frag from Vt.
#pragma unroll
    for (int ks = 0; ks < 2; ++ks) {
      half8 ea = *(const half8*)&El[l15][c * 64 + ks * 32 + lg * 8];
      half8 vb = *(const half8*)&Vt[w * 16 + l15][ks * 32 + lg * 8];
      oacc = __builtin_amdgcn_mfma_f32_16x16x32_f16(ea, vb, oacc, 0, 0, 0);
    }

    __syncthreads();                       // V(c)/E reads done
    if (c < 15) { kwrite(); vwrite(); }    // stage tile c+1
  }

  // Z exchange: zsum covers (q=l15, this wave's t-set); reduce lg then waves
  zsum += __shfl_xor(zsum, 16, 64);
  zsum += __shfl_xor(zsum, 32, 64);
  if (lg == 0) zb[w][l15] = zsum;
  __syncthreads();

  // out store: oacc[i] = O[q=lg*4+i][d=w*16+l15] (unnormalized)
  {
    float* ob = out + ((size_t)hb * L_ + ltile * QB) * (size_t)D_;
#pragma unroll
    for (int i = 0; i < 4; ++i) {
      const int qq = lg * 4 + i;
      float z = (zb[0][qq] + zb[1][qq]) + (zb[2][qq] + zb[3][qq]);
      ob[(size_t)qq * D_ + w * 16 + l15] = oacc[i] / z;
    }
  }

  // Phase B: barrier-free normalized att streaming.
  // thread -> row = tid>>4, t columns tc*4 + j*64 (1KB/instr coalesced)
  {
    const int row = tid >> 4, tc = tid & 15;
    const float z =
        (zb[0][row] + zb[1][row]) + (zb[2][row] + zb[3][row]);
    const float rzr = 1.0f / z;
    float* attw =
        att + ((size_t)hb * L_ + ltile * QB + row) * (size_t)T_ + tc * 4;
    const _Float16* ep = &El[row][tc * 4];
#pragma unroll
    for (int j = 0; j < 16; ++j) {
      half4 ev = *(const half4*)(ep + j * 64);
      f32x4 s = {(float)ev[0] * rzr, (float)ev[1] * rzr,
                 (float)ev[2] * rzr, (float)ev[3] * rzr};
      *(f32x4*)(attw + j * 64) = s;
    }
  }
}

extern "C" void kernel_launch(void* const* d_in, const int* in_sizes, int n_in,
                              void* d_out, int out_size, void* d_ws,
                              size_t ws_size, hipStream_t stream) {
  const float* q    = (const float*)d_in[0];  // (H,B,L,D)
  const float* k    = (const float*)d_in[1];  // (H,B,T,D)
  const float* v    = (const float*)d_in[2];  // (H,B,T,D)
  const float* prev = (const float*)d_in[3];  // (H,B,L,T)

  float* out = (float*)d_out;                 // (H,B,L,D)
  float* att = out + (size_t)HB_ * L_ * D_;   // (H,B,L,T)

  dim3 grid(L_ / QB, HB_);
  attn_fused<<<grid, 256, 0, stream>>>(q, k, v, prev, out, att);
}